// Round 11
// baseline (167.573 us; speedup 1.0000x reference)
//
#include <hip/hip_runtime.h>
#include <cstddef>

typedef _Float16 f16x8 __attribute__((ext_vector_type(8)));
typedef __attribute__((ext_vector_type(4))) float f32x4;

#define MFMA(a, b, c) __builtin_amdgcn_mfma_f32_16x16x32_f16((a), (b), (c), 0, 0, 0)

static constexpr float LO_SCALE = 2048.0f;   // 2^11 keeps weight-lo fp16-normal
static constexpr float LO_INV   = 1.0f / 2048.0f;

static __device__ __forceinline__ unsigned f2h_bits(float f) {
  _Float16 h = (_Float16)f;
  return (unsigned)__builtin_bit_cast(unsigned short, h);
}
static __device__ __forceinline__ unsigned pack16(unsigned a, unsigned b) {
  return __builtin_amdgcn_perm(b, a, 0x05040100u);
}
static __device__ __forceinline__ void wsplit(float v, _Float16& hi, _Float16& lo) {
  _Float16 h = (_Float16)v;
  hi = h;
  lo = (_Float16)((v - (float)h) * LO_SCALE);
}

// merged-rcp LSTM cell: c' = c*sig(f) + sig(i)*tanh(g); returns h = sig(o)*tanh(c').
// sig/tanh expanded over common denominators: 5 exp + 2 rcp (vs 5 exp + 5 rcp).
static __device__ __forceinline__ float cell_update(float gi, float gf, float gg,
                                                    float go, float& c) {
  float ei = __expf(-gi), ef = __expf(-gf);
  float eg = __expf(-2.0f * gg), eo = __expf(-go);
  float Di = 1.0f + ei, Df = 1.0f + ef, Dg = 1.0f + eg;
  float t1  = Di * Dg;
  float num = fmaf(1.0f - eg, Df, c * t1);
  c = num * __builtin_amdgcn_rcpf(Df * t1);
  float ec = __expf(-2.0f * c);
  return (1.0f - ec) * __builtin_amdgcn_rcpf((1.0f + eo) * (1.0f + ec));
}

// LDS-only barrier (R5/R7/R9-verified)
static __device__ __forceinline__ void lds_barrier() {
  asm volatile("s_waitcnt lgkmcnt(0)\n\ts_barrier" ::: "memory");
}

// Activation buffer: [16 batch rows][256 B = 128 fp16 k-slots], XOR-swizzled per row.
static __device__ __forceinline__ f16x8 aread(const char* base, int lane, int kc) {
  int b = lane & 15, g = lane >> 4;
  int off = (kc * 64 + g * 16) ^ ((b & 7) << 4);
  return *(const f16x8*)(base + b * 256 + off);
}
static __device__ __forceinline__ void awrite16(char* base, int b, int k, unsigned short v) {
  int off = (2 * k) ^ ((b & 7) << 4);
  *(unsigned short*)(base + b * 256 + off) = v;
}

// 16 waves (1024 thr), 16 batch/block, grid 256 -> 4 waves/SIMD, 1 n-frag/wave.
// fp16 scheme (R9-verified): weights = A-operand hi + lo*2^-11 in VGPRs; activations =
// single fp16 plane in LDS (B-operand, cols = batch); in-register merged-rcp cell update.
// Encoder: 1 lds_barrier/step. Phase 2: lagged pipeline (latent t=i on w<8 | decoder
// t=i-1 all waves | projection t=i-2 on w>=13), 1 lds_barrier/iter.
extern "C" __global__ __launch_bounds__(1024, 1)
void lstm_ae_mfma10(const float* __restrict__ x,
                    const float* __restrict__ eWih, const float* __restrict__ eWhh, const float* __restrict__ eb,
                    const float* __restrict__ lWih, const float* __restrict__ lWhh, const float* __restrict__ lb,
                    const float* __restrict__ dWih, const float* __restrict__ dWhh, const float* __restrict__ db,
                    const float* __restrict__ oW,  const float* __restrict__ ob,
                    float* __restrict__ out)
{
  __shared__ __align__(16) char sA[2][4096];

  const int tid  = threadIdx.x;
  const int lane = tid & 63;
  const int w    = tid >> 6;        // wave 0..15
  const int c16  = lane & 15;       // batch (B-frag col / C-D col)
  const int p4   = lane >> 4;
  const int bbase = blockIdx.x * 16;
  const int ga   = c16 & 3;         // gate row within unit (i,f,g,o)

  // ---------- zero both buffers (8 KB) ----------
  if (tid < 512) {
    f32x4 z = {0.f, 0.f, 0.f, 0.f};
    *(f32x4*)(&sA[0][0] + tid * 16) = z;
  }

  // ---------- encoder weights: 1 frag/wave. ghat = w*16 + c16 -> u = w*4+(c16>>2) ----------
  // k: 0..39 = x (chunks 0,1), 64..127 = h_enc slot 64+u (chunks 2,3)
  f16x8 ewh[4], ewl[4];
  float ebias[4];
  {
    int u = w * 4 + (c16 >> 2);
#pragma unroll
    for (int r = 0; r < 4; ++r) ebias[r] = eb[r * 64 + (w * 4 + p4)];
#pragma unroll
    for (int kc = 0; kc < 4; ++kc) {
      f16x8 hi, lo;
#pragma unroll
      for (int e = 0; e < 8; ++e) {
        int k = kc * 32 + p4 * 8 + e;
        float v = 0.f;
        if (k < 40)       v = eWih[(ga * 64 + u) * 40 + k];
        else if (k >= 64) v = eWhh[(ga * 64 + u) * 64 + (k - 64)];
        _Float16 h, l;
        wsplit(v, h, l);
        hi[e] = h; lo[e] = l;
      }
      ewh[kc] = hi; ewl[kc] = lo;
    }
  }

  lds_barrier();  // zeros visible

  // ---------- stage x(0) into buf 0 (160 threads, 4 floats each) ----------
  const bool stager = (tid < 160);
  const int sb = tid / 10, sf4 = tid - (tid / 10) * 10;
  if (stager) {
    f32x4 ld = *(const f32x4*)(x + ((size_t)(bbase + sb) * 100 + 0) * 40 + sf4 * 4);
    unsigned long long pv =
        (unsigned long long)pack16(f2h_bits(ld[0]), f2h_bits(ld[1]))
      | ((unsigned long long)pack16(f2h_bits(ld[2]), f2h_bits(ld[3])) << 32);
    int off = (sf4 * 8) ^ ((sb & 7) << 4);
    *(unsigned long long*)(sA[0] + sb * 256 + off) = pv;
  }

  float cE = 0.f;
  int q = 0;
  lds_barrier();

  // ================= PHASE 1: encoder, 1 lds_barrier/step =================
#pragma unroll 1
  for (int t = 0; t < 100; ++t) {
    f32x4 xld;
    if (stager) {
      int tn = (t + 1 < 100) ? t + 1 : 99;
      xld = *(const f32x4*)(x + ((size_t)(bbase + sb) * 100 + tn) * 40 + sf4 * 4);
    }

    f32x4 acc  = f32x4{ebias[0], ebias[1], ebias[2], ebias[3]};
    f32x4 accL = {0.f, 0.f, 0.f, 0.f};
    const char* A = sA[q];
#pragma unroll
    for (int kc = 0; kc < 4; ++kc) {
      f16x8 a = aread(A, lane, kc);
      acc  = MFMA(ewh[kc], a, acc);
      accL = MFMA(ewl[kc], a, accL);
    }

    char* AN = sA[q ^ 1];
    {
      f32x4 gv = acc + accL * LO_INV;
      float hv = cell_update(gv[0], gv[1], gv[2], gv[3], cE);
      awrite16(AN, c16, 64 + w * 4 + p4, (unsigned short)f2h_bits(hv));
    }

    if (stager) {
      unsigned long long pv =
          (unsigned long long)pack16(f2h_bits(xld[0]), f2h_bits(xld[1]))
        | ((unsigned long long)pack16(f2h_bits(xld[2]), f2h_bits(xld[3])) << 32);
      int off = (sf4 * 8) ^ ((sb & 7) << 4);
      *(unsigned long long*)(AN + sb * 256 + off) = pv;
    }
    lds_barrier();
    q ^= 1;
  }
  // h(99) in buf[q] chunks 2,3.

  // ================= xg_lat = lb + lWih @ h_enc_last (waves 0..7, 1 frag) =================
  f32x4 xga = {0.f, 0.f, 0.f, 0.f};
  if (w < 8) {
    int u = w * 4 + (c16 >> 2);           // latent unit 0..31
    int ul = w * 4 + p4;
    xga = f32x4{lb[ul], lb[32 + ul], lb[64 + ul], lb[96 + ul]};
    f32x4 xgaL = {0.f, 0.f, 0.f, 0.f};
#pragma unroll
    for (int kci = 0; kci < 2; ++kci) {
      f16x8 hi, lo;
#pragma unroll
      for (int e = 0; e < 8; ++e) {
        float v = lWih[(ga * 32 + u) * 64 + kci * 32 + p4 * 8 + e];
        _Float16 h, l;
        wsplit(v, h, l);
        hi[e] = h; lo[e] = l;
      }
      f16x8 a = aread(sA[q], lane, 2 + kci);
      xga  = MFMA(hi, a, xga);
      xgaL = MFMA(lo, a, xgaL);
    }
    xga = xga + xgaL * LO_INV;
  }
  lds_barrier();  // h_enc reads complete before re-zero

  // re-zero both buffers (h_lat(-1) = h_dec(-1) = h_dec(-2) = 0)
  if (tid < 512) {
    f32x4 z = {0.f, 0.f, 0.f, 0.f};
    *(f32x4*)(&sA[0][0] + tid * 16) = z;
  }

  // ---------- phase-2 weights ----------
  // latent Whh (waves 0..7): u = w*4+(c16>>2), k 0..31 = h_lat slot u
  f16x8 lwh = {}, lwl = {};
  if (w < 8) {
    int u = w * 4 + (c16 >> 2);
    f16x8 hi, lo;
#pragma unroll
    for (int e = 0; e < 8; ++e) {
      float v = lWhh[(ga * 32 + u) * 32 + p4 * 8 + e];
      _Float16 h, l;
      wsplit(v, h, l);
      hi[e] = h; lo[e] = l;
    }
    lwh = hi; lwl = lo;
  }
  // decoder (all 16 waves, 1 frag): u = w*4+(c16>>2); k: 0..31 h_lat, 32..95 h_dec
  f16x8 dwh[3], dwl[3];
  float dbias[4];
  {
    int u = w * 4 + (c16 >> 2);
#pragma unroll
    for (int r = 0; r < 4; ++r) dbias[r] = db[r * 64 + (w * 4 + p4)];
#pragma unroll
    for (int kc = 0; kc < 3; ++kc) {
      f16x8 hi, lo;
#pragma unroll
      for (int e = 0; e < 8; ++e) {
        int k = kc * 32 + p4 * 8 + e;
        float v = (k < 32) ? dWih[(ga * 64 + u) * 32 + k]
                           : dWhh[(ga * 64 + u) * 64 + (k - 32)];
        _Float16 h, l;
        wsplit(v, h, l);
        hi[e] = h; lo[e] = l;
      }
      dwh[kc] = hi; dwl[kc] = lo;
    }
  }
  // projection (waves 13..15): f = (w-13)*16 + c16; k chunks 1,2 = h_dec 0..63
  f16x8 pwh[2] = {}, pwl[2] = {};
  float pbias[4];
  const int wp = w - 13;
#pragma unroll
  for (int r = 0; r < 4; ++r) {
    int f = wp * 16 + p4 * 4 + r;
    pbias[r] = (w >= 13 && f < 40) ? ob[f] : 0.0f;
  }
  if (w >= 13) {
    int f = wp * 16 + c16;
#pragma unroll
    for (int kci = 0; kci < 2; ++kci) {
      f16x8 hi, lo;
#pragma unroll
      for (int e = 0; e < 8; ++e) {
        float v = (f < 40) ? oW[f * 64 + kci * 32 + p4 * 8 + e] : 0.0f;
        _Float16 h, l;
        wsplit(v, h, l);
        hi[e] = h; lo[e] = l;
      }
      pwh[kci] = hi; pwl[kci] = lo;
    }
  }

  float cL = 0.f, cD = 0.f;
  lds_barrier();

  // ================= PHASE 2: lagged pipeline, 1 lds_barrier/iter =================
  // iter i: latent t=i (w<8) | decoder t=i-1 (all) | projection t=i-2 (w>=13).
  // h_lat(t) -> buf[t&1] k 0..31; h_dec(t) -> buf[t&1] k 32..95.
#pragma unroll 1
  for (int i = 0; i < 102; ++i) {
    const int pa = i & 1;
    f16x8 c0 = aread(sA[pa ^ 1], lane, 0);
    f16x8 d1 = aread(sA[pa], lane, 1);
    f16x8 d2 = aread(sA[pa], lane, 2);

    // --- latent step t=i (waves 0..7; reads h_lat(i-1) = c0) ---
    if (i < 100 && w < 8) {
      f32x4 lac = xga, lacL = {0.f, 0.f, 0.f, 0.f};
      lac  = MFMA(lwh, c0, lac);
      lacL = MFMA(lwl, c0, lacL);
      f32x4 gv = lac + lacL * LO_INV;
      float hv = cell_update(gv[0], gv[1], gv[2], gv[3], cL);
      awrite16(sA[pa], c16, w * 4 + p4, (unsigned short)f2h_bits(hv));
    }

    // --- decoder step t=i-1 (all waves; reads c0 + h_dec(i-2) = d1,d2) ---
    if (i >= 1 && i < 101) {
      f32x4 dac = f32x4{dbias[0], dbias[1], dbias[2], dbias[3]};
      f32x4 dacL = {0.f, 0.f, 0.f, 0.f};
      dac  = MFMA(dwh[0], c0, dac);
      dacL = MFMA(dwl[0], c0, dacL);
      dac  = MFMA(dwh[1], d1, dac);
      dacL = MFMA(dwl[1], d1, dacL);
      dac  = MFMA(dwh[2], d2, dac);
      dacL = MFMA(dwl[2], d2, dacL);
      f32x4 gv = dac + dacL * LO_INV;
      float hv = cell_update(gv[0], gv[1], gv[2], gv[3], cD);
      awrite16(sA[pa ^ 1], c16, 32 + w * 4 + p4, (unsigned short)f2h_bits(hv));
    }

    // --- projection t=i-2 (waves 13..15; shares d1,d2 reads) ---
    if (i >= 2 && w >= 13) {
      f32x4 pac = f32x4{pbias[0], pbias[1], pbias[2], pbias[3]};
      f32x4 pacL = {0.f, 0.f, 0.f, 0.f};
      pac  = MFMA(pwh[0], d1, pac);
      pacL = MFMA(pwl[0], d1, pacL);
      pac  = MFMA(pwh[1], d2, pac);
      pacL = MFMA(pwl[1], d2, pacL);
      f32x4 pv = pac + pacL * LO_INV;
#pragma unroll
      for (int r = 0; r < 4; ++r) {
        int f = wp * 16 + p4 * 4 + r;
        if (f < 40)
          out[((size_t)(bbase + c16) * 100 + (i - 2)) * 40 + f] = pv[r];
      }
    }
    lds_barrier();
  }
}

extern "C" void kernel_launch(void* const* d_in, const int* in_sizes, int n_in,
                              void* d_out, int out_size, void* d_ws, size_t ws_size,
                              hipStream_t stream) {
  const float* x    = (const float*)d_in[0];
  const float* eWih = (const float*)d_in[1];
  const float* eWhh = (const float*)d_in[2];
  const float* eb   = (const float*)d_in[3];
  const float* lWih = (const float*)d_in[4];
  const float* lWhh = (const float*)d_in[5];
  const float* lb   = (const float*)d_in[6];
  const float* dWih = (const float*)d_in[7];
  const float* dWhh = (const float*)d_in[8];
  const float* db   = (const float*)d_in[9];
  const float* oW   = (const float*)d_in[10];
  const float* ob   = (const float*)d_in[11];
  float* out = (float*)d_out;

  lstm_ae_mfma10<<<256, 1024, 0, stream>>>(x, eWih, eWhh, eb, lWih, lWhh, lb,
                                           dWih, dWhh, db, oW, ob, out);
}

// Round 12
// 157.141 us; speedup vs baseline: 1.0664x; 1.0664x over previous
//
#include <hip/hip_runtime.h>
#include <cstddef>

typedef _Float16 f16x8 __attribute__((ext_vector_type(8)));
typedef __attribute__((ext_vector_type(4))) float f32x4;

#define MFMA(a, b, c) __builtin_amdgcn_mfma_f32_16x16x32_f16((a), (b), (c), 0, 0, 0)

static constexpr float LO_SCALE = 2048.0f;   // 2^11 keeps weight-lo fp16-normal
static constexpr float LO_INV   = 1.0f / 2048.0f;

static __device__ __forceinline__ unsigned f2h_bits(float f) {
  _Float16 h = (_Float16)f;
  return (unsigned)__builtin_bit_cast(unsigned short, h);
}
static __device__ __forceinline__ unsigned pack16(unsigned a, unsigned b) {
  return __builtin_amdgcn_perm(b, a, 0x05040100u);
}
static __device__ __forceinline__ void wsplit(float v, _Float16& hi, _Float16& lo) {
  _Float16 h = (_Float16)v;
  hi = h;
  lo = (_Float16)((v - (float)h) * LO_SCALE);
}

// merged-rcp LSTM cell: c' = c*sig(f) + sig(i)*tanh(g); returns h = sig(o)*tanh(c').
// Expanded over common denominators: 5 exp + 2 rcp (vs 5 exp + 5 rcp).
static __device__ __forceinline__ float cell_update(float gi, float gf, float gg,
                                                    float go, float& c) {
  float ei = __expf(-gi), ef = __expf(-gf);
  float eg = __expf(-2.0f * gg), eo = __expf(-go);
  float Di = 1.0f + ei, Df = 1.0f + ef, Dg = 1.0f + eg;
  float t1  = Di * Dg;
  float num = fmaf(1.0f - eg, Df, c * t1);
  c = num * __builtin_amdgcn_rcpf(Df * t1);
  float ec = __expf(-2.0f * c);
  return (1.0f - ec) * __builtin_amdgcn_rcpf((1.0f + eo) * (1.0f + ec));
}

// LDS-only barrier (R5/R7/R9-verified)
static __device__ __forceinline__ void lds_barrier() {
  asm volatile("s_waitcnt lgkmcnt(0)\n\ts_barrier" ::: "memory");
}

// Activation buffer: [16 batch rows][256 B = 128 fp16 k-slots], XOR-swizzled per row.
// B-fragment (cols = batch): lane holds col b=lane&15, k = kc*32 + (lane>>4)*8 + {0..7}.
static __device__ __forceinline__ f16x8 aread(const char* base, int lane, int kc) {
  int b = lane & 15, g = lane >> 4;
  int off = (kc * 64 + g * 16) ^ ((b & 7) << 4);
  return *(const f16x8*)(base + b * 256 + off);
}
static __device__ __forceinline__ void awrite16(char* base, int b, int k, unsigned short v) {
  int off = (2 * k) ^ ((b & 7) << 4);
  *(unsigned short*)(base + b * 256 + off) = v;
}
static __device__ __forceinline__ void awrite32(char* base, int b, int k, unsigned v) {
  int off = (2 * k) ^ ((b & 7) << 4);
  *(unsigned*)(base + b * 256 + off) = v;
}

// 8 waves, 16 batch/block, grid 256 (R9-verified structure). fp16 scheme: weights =
// A-operand hi + lo*2^-11 in VGPRs (2 n-frags/wave); activations = single fp16 plane in
// LDS (B-operand, cols = batch); in-register merged-rcp cell update. Stager spread over
// 320 threads x float2. Encoder: 1 lds_barrier/step. Phase 2: lagged pipeline
// (latent t=i | decoder t=i-1 | projection t=i-2), 1 lds_barrier/iter.
extern "C" __global__ __launch_bounds__(512, 2)
void lstm_ae_mfma11(const float* __restrict__ x,
                    const float* __restrict__ eWih, const float* __restrict__ eWhh, const float* __restrict__ eb,
                    const float* __restrict__ lWih, const float* __restrict__ lWhh, const float* __restrict__ lb,
                    const float* __restrict__ dWih, const float* __restrict__ dWhh, const float* __restrict__ db,
                    const float* __restrict__ oW,  const float* __restrict__ ob,
                    float* __restrict__ out)
{
  __shared__ __align__(16) char sA[2][4096];

  const int tid  = threadIdx.x;
  const int lane = tid & 63;
  const int w    = tid >> 6;        // wave 0..7
  const int c16  = lane & 15;       // batch
  const int p4   = lane >> 4;
  const int bbase = blockIdx.x * 16;
  const int ga   = c16 & 3;

  // ---------- zero both buffers (8 KB) ----------
  {
    f32x4 z = {0.f, 0.f, 0.f, 0.f};
    *(f32x4*)(&sA[0][0] + tid * 16) = z;
  }

  // ---------- encoder weights: rows tr=c16 -> (u = w*8+(tr>>2)*2+n, ga = tr&3) ----------
  // k: 0..39 = x (chunks 0,1), 64..127 = h_enc slot 64+u (chunks 2,3)
  f16x8 ewh[2][4], ewl[2][4];
  float ebias[2][4];
#pragma unroll
  for (int n = 0; n < 2; ++n) {
    int u = w * 8 + (c16 >> 2) * 2 + n;
#pragma unroll
    for (int r = 0; r < 4; ++r) ebias[n][r] = eb[r * 64 + (w * 8 + p4 * 2 + n)];
#pragma unroll
    for (int kc = 0; kc < 4; ++kc) {
      f16x8 hi, lo;
#pragma unroll
      for (int e = 0; e < 8; ++e) {
        int k = kc * 32 + p4 * 8 + e;
        float v = 0.f;
        if (k < 40)       v = eWih[(ga * 64 + u) * 40 + k];
        else if (k >= 64) v = eWhh[(ga * 64 + u) * 64 + (k - 64)];
        _Float16 h, l;
        wsplit(v, h, l);
        hi[e] = h; lo[e] = l;
      }
      ewh[n][kc] = hi; ewl[n][kc] = lo;
    }
  }

  lds_barrier();  // zeros visible

  // ---------- stage x(0) into buf 0 (320 threads, float2 each) ----------
  const bool stager = (tid < 320);
  const int sb = tid / 20, sf0 = (tid % 20) * 2;
  if (stager) {
    float2 v = *(const float2*)(x + ((size_t)(bbase + sb) * 100 + 0) * 40 + sf0);
    awrite32(sA[0], sb, sf0, pack16(f2h_bits(v.x), f2h_bits(v.y)));
  }

  float cE[2] = {0.f, 0.f};
  int q = 0;
  lds_barrier();

  // ================= PHASE 1: encoder, 1 lds_barrier/step =================
#pragma unroll 1
  for (int t = 0; t < 100; ++t) {
    float2 xld;
    if (stager) {
      int tn = (t + 1 < 100) ? t + 1 : 99;
      xld = *(const float2*)(x + ((size_t)(bbase + sb) * 100 + tn) * 40 + sf0);
    }

    f32x4 acc[2], accL[2];
#pragma unroll
    for (int n = 0; n < 2; ++n) {
      acc[n]  = f32x4{ebias[n][0], ebias[n][1], ebias[n][2], ebias[n][3]};
      accL[n] = f32x4{0.f, 0.f, 0.f, 0.f};
    }
    const char* A = sA[q];
#pragma unroll
    for (int kc = 0; kc < 4; ++kc) {
      f16x8 a = aread(A, lane, kc);
#pragma unroll
      for (int n = 0; n < 2; ++n) {
        acc[n]  = MFMA(ewh[n][kc], a, acc[n]);
        accL[n] = MFMA(ewl[n][kc], a, accL[n]);
      }
    }

    char* AN = sA[q ^ 1];
    unsigned hb[2];
#pragma unroll
    for (int n = 0; n < 2; ++n) {
      f32x4 gv = acc[n] + accL[n] * LO_INV;
      float hv = cell_update(gv[0], gv[1], gv[2], gv[3], cE[n]);
      hb[n] = f2h_bits(hv);
    }
    awrite32(AN, c16, 64 + w * 8 + p4 * 2, pack16(hb[0], hb[1]));

    if (stager)
      awrite32(AN, sb, sf0, pack16(f2h_bits(xld.x), f2h_bits(xld.y)));
    lds_barrier();
    q ^= 1;
  }
  // h(99) in buf[q] chunks 2,3.

  // ================= xg_lat = lb + lWih @ h_enc_last =================
  f32x4 xga;
  {
    int u = w * 4 + (c16 >> 2);
    int ul = w * 4 + p4;
    xga = f32x4{lb[ul], lb[32 + ul], lb[64 + ul], lb[96 + ul]};
    f32x4 xgaL = {0.f, 0.f, 0.f, 0.f};
#pragma unroll
    for (int kci = 0; kci < 2; ++kci) {
      f16x8 hi, lo;
#pragma unroll
      for (int e = 0; e < 8; ++e) {
        float v = lWih[(ga * 32 + u) * 64 + kci * 32 + p4 * 8 + e];
        _Float16 h, l;
        wsplit(v, h, l);
        hi[e] = h; lo[e] = l;
      }
      f16x8 a = aread(sA[q], lane, 2 + kci);
      xga  = MFMA(hi, a, xga);
      xgaL = MFMA(lo, a, xgaL);
    }
    xga = xga + xgaL * LO_INV;
  }
  lds_barrier();  // h_enc reads complete before re-zero

  // re-zero both buffers (h_lat(-1) = h_dec(-1) = h_dec(-2) = 0)
  {
    f32x4 z = {0.f, 0.f, 0.f, 0.f};
    *(f32x4*)(&sA[0][0] + tid * 16) = z;
  }

  // ---------- phase-2 weights ----------
  f16x8 lwh, lwl;
  {
    int u = w * 4 + (c16 >> 2);
    f16x8 hi, lo;
#pragma unroll
    for (int e = 0; e < 8; ++e) {
      float v = lWhh[(ga * 32 + u) * 32 + p4 * 8 + e];
      _Float16 h, l;
      wsplit(v, h, l);
      hi[e] = h; lo[e] = l;
    }
    lwh = hi; lwl = lo;
  }
  f16x8 dwh[2][3], dwl[2][3];
  float dbias[2][4];
#pragma unroll
  for (int n = 0; n < 2; ++n) {
    int u = w * 8 + (c16 >> 2) * 2 + n;
#pragma unroll
    for (int r = 0; r < 4; ++r) dbias[n][r] = db[r * 64 + (w * 8 + p4 * 2 + n)];
#pragma unroll
    for (int kc = 0; kc < 3; ++kc) {
      f16x8 hi, lo;
#pragma unroll
      for (int e = 0; e < 8; ++e) {
        int k = kc * 32 + p4 * 8 + e;
        float v = (k < 32) ? dWih[(ga * 64 + u) * 32 + k]
                           : dWhh[(ga * 64 + u) * 64 + (k - 32)];
        _Float16 h, l;
        wsplit(v, h, l);
        hi[e] = h; lo[e] = l;
      }
      dwh[n][kc] = hi; dwl[n][kc] = lo;
    }
  }
  f16x8 pwh[2], pwl[2];
  float pbias[4];
#pragma unroll
  for (int r = 0; r < 4; ++r) {
    int f = w * 16 + p4 * 4 + r;
    pbias[r] = (w < 3 && f < 40) ? ob[f] : 0.0f;
  }
  if (w < 3) {
    int f = w * 16 + c16;
#pragma unroll
    for (int kci = 0; kci < 2; ++kci) {
      f16x8 hi, lo;
#pragma unroll
      for (int e = 0; e < 8; ++e) {
        float v = (f < 40) ? oW[f * 64 + kci * 32 + p4 * 8 + e] : 0.0f;
        _Float16 h, l;
        wsplit(v, h, l);
        hi[e] = h; lo[e] = l;
      }
      pwh[kci] = hi; pwl[kci] = lo;
    }
  }

  float cL = 0.f;
  float cD[2] = {0.f, 0.f};
  lds_barrier();

  // ================= PHASE 2: lagged pipeline, 1 lds_barrier/iter =================
  // iter i: latent t=i | decoder t=i-1 | projection t=i-2.
  // h_lat(t) -> buf[t&1] k 0..31; h_dec(t) -> buf[t&1] k 32..95.
#pragma unroll 1
  for (int i = 0; i < 102; ++i) {
    const int pa = i & 1;
    f16x8 c0 = aread(sA[pa ^ 1], lane, 0);
    f16x8 d1 = aread(sA[pa], lane, 1);
    f16x8 d2 = aread(sA[pa], lane, 2);

    // --- latent step t=i (reads h_lat(i-1) = c0) ---
    if (i < 100) {
      f32x4 lac = xga, lacL = {0.f, 0.f, 0.f, 0.f};
      lac  = MFMA(lwh, c0, lac);
      lacL = MFMA(lwl, c0, lacL);
      f32x4 gv = lac + lacL * LO_INV;
      float hv = cell_update(gv[0], gv[1], gv[2], gv[3], cL);
      awrite16(sA[pa], c16, w * 4 + p4, (unsigned short)f2h_bits(hv));
    }

    // --- decoder step t=i-1 (reads h_lat(i-1) = c0, h_dec(i-2) = d1,d2) ---
    if (i >= 1 && i < 101) {
      unsigned hb[2];
#pragma unroll
      for (int n = 0; n < 2; ++n) {
        f32x4 dac = f32x4{dbias[n][0], dbias[n][1], dbias[n][2], dbias[n][3]};
        f32x4 dacL = {0.f, 0.f, 0.f, 0.f};
        dac  = MFMA(dwh[n][0], c0, dac);
        dacL = MFMA(dwl[n][0], c0, dacL);
        dac  = MFMA(dwh[n][1], d1, dac);
        dacL = MFMA(dwl[n][1], d1, dacL);
        dac  = MFMA(dwh[n][2], d2, dac);
        dacL = MFMA(dwl[n][2], d2, dacL);
        f32x4 gv = dac + dacL * LO_INV;
        float hv = cell_update(gv[0], gv[1], gv[2], gv[3], cD[n]);
        hb[n] = f2h_bits(hv);
      }
      awrite32(sA[pa ^ 1], c16, 32 + w * 8 + p4 * 2, pack16(hb[0], hb[1]));
    }

    // --- projection t=i-2 (reads h_dec(i-2) = d1,d2; shares the reads) ---
    if (i >= 2 && w < 3) {
      f32x4 pac = f32x4{pbias[0], pbias[1], pbias[2], pbias[3]};
      f32x4 pacL = {0.f, 0.f, 0.f, 0.f};
      pac  = MFMA(pwh[0], d1, pac);
      pacL = MFMA(pwl[0], d1, pacL);
      pac  = MFMA(pwh[1], d2, pac);
      pacL = MFMA(pwl[1], d2, pacL);
      f32x4 pv = pac + pacL * LO_INV;
#pragma unroll
      for (int r = 0; r < 4; ++r) {
        int f = w * 16 + p4 * 4 + r;
        if (f < 40)
          out[((size_t)(bbase + c16) * 100 + (i - 2)) * 40 + f] = pv[r];
      }
    }
    lds_barrier();
  }
}

extern "C" void kernel_launch(void* const* d_in, const int* in_sizes, int n_in,
                              void* d_out, int out_size, void* d_ws, size_t ws_size,
                              hipStream_t stream) {
  const float* x    = (const float*)d_in[0];
  const float* eWih = (const float*)d_in[1];
  const float* eWhh = (const float*)d_in[2];
  const float* eb   = (const float*)d_in[3];
  const float* lWih = (const float*)d_in[4];
  const float* lWhh = (const float*)d_in[5];
  const float* lb   = (const float*)d_in[6];
  const float* dWih = (const float*)d_in[7];
  const float* dWhh = (const float*)d_in[8];
  const float* db   = (const float*)d_in[9];
  const float* oW   = (const float*)d_in[10];
  const float* ob   = (const float*)d_in[11];
  float* out = (float*)d_out;

  lstm_ae_mfma11<<<256, 512, 0, stream>>>(x, eWih, eWhh, eb, lWih, lWhh, lb,
                                          dWih, dWhh, db, oW, ob, out);
}